// Round 1
// baseline (8002.190 us; speedup 1.0000x reference)
//
#include <hip/hip_runtime.h>
#include <math.h>

#define EPSV 1e-5f

// ---------------------------------------------------------------------------
// Axial attention megakernel: one block per column (n, col), 256 threads.
//  WIDTH=false: attention along h (y); column = fixed x. Reads original x with
//               patchify indexing, writes p.
//  WIDTH=true : attention along w (x); column = fixed y. Reads p (in place,
//               row-disjoint across blocks), adds residual (patchified x).
// LDS: Xs 256x44 (input column) + qb 64x44 (q,k then v) + sc 44x44 = 64,064 B
// ---------------------------------------------------------------------------
template<bool WIDTH>
__global__ __launch_bounds__(256)
void axial_kernel(const float* __restrict__ src,
                  const float* __restrict__ xres,
                  float* __restrict__ pout,
                  const float* __restrict__ Wq,    // 512x256
                  const float* __restrict__ bnq,   // 4x512 (gamma,beta,mean,var)
                  const float* __restrict__ bns,   // 4x12
                  const float* __restrict__ bno,   // 4x512
                  const float* __restrict__ rel)   // 128x87
{
    __shared__ __align__(16) float Xs[256][44];
    __shared__ __align__(16) float qb[64][44];
    __shared__ __align__(16) float sc[44][44];

    const int blk = blockIdx.x;
    const int n   = blk / 44;
    const int col = blk - n * 44;
    const int b = n >> 2, i2 = (n >> 1) & 1, i4 = n & 1;
    const int t = threadIdx.x;

    // ---- stage X[c][i] ----
    if (!WIDTH) {
        // X[c][i] = x[b, c, i2*44 + i, i4*44 + col]
        const float* base = src + ((b * 256) * 88 + i2 * 44) * 88 + i4 * 44 + col;
        for (int e = t; e < 256 * 44; e += 256) {
            int c = e / 44, i = e - c * 44;
            Xs[c][i] = base[c * 7744 + i * 88];
        }
    } else {
        // X[c][i] = p[n, c, col, i]
        const float* base = src + ((n * 256) * 44 + col) * 44;
        for (int e = t; e < 256 * 44; e += 256) {
            int c = e / 44, i = e - c * 44;
            Xs[c][i] = base[c * 1936 + i];
        }
    }
    __syncthreads();

    for (int g = 0; g < 4; ++g) {
        // ---- q,k rows: W rows g*128 + [0,64), BN fused ----
        for (int u = t; u < 704; u += 256) {
            int oc = u / 11, iq = u - oc * 11, i0 = iq * 4;
            int o = g * 128 + oc;
            const float* wrow = Wq + o * 256;
            float a0 = 0.f, a1 = 0.f, a2 = 0.f, a3 = 0.f;
            #pragma unroll 4
            for (int c = 0; c < 256; ++c) {
                float wv = wrow[c];
                float4 xv = *(const float4*)&Xs[c][i0];
                a0 += wv * xv.x; a1 += wv * xv.y; a2 += wv * xv.z; a3 += wv * xv.w;
            }
            float s = bnq[o] * rsqrtf(bnq[1536 + o] + EPSV);
            float h = bnq[512 + o] - bnq[1024 + o] * s;
            *(float4*)&qb[oc][i0] = make_float4(a0 * s + h, a1 * s + h, a2 * s + h, a3 * s + h);
        }
        __syncthreads();

        // ---- scores: sc[i][j] = sqk*qk + 0.1*(sqr*qr + skr*kr)  (BN const dropped: exact under softmax) ----
        const float sqk = bns[g]     * rsqrtf(bns[36 + g] + EPSV);
        const float sqr = bns[4 + g] * rsqrtf(bns[40 + g] + EPSV);
        const float skr = bns[8 + g] * rsqrtf(bns[44 + g] + EPSV);

        for (int e = t; e < 1936; e += 256) {
            int i = e / 44, j = e - i * 44;
            const float* relq = rel + (i - j + 43);            // rows 0..31
            const float* relk = rel + 32 * 87 + (j - i + 43);  // rows 32..63
            float aqk = 0.f, aqr = 0.f, akr = 0.f;
            #pragma unroll 4
            for (int c = 0; c < 32; ++c) {
                float qi = qb[c][i], kj = qb[32 + c][j];
                aqk += qi * kj;
                aqr += qi * relq[c * 87];
                akr += kj * relk[c * 87];
            }
            sc[i][j] = sqk * aqk + 0.1f * (sqr * aqr + skr * akr);
        }
        __syncthreads();

        // ---- v rows overwrite qb: W rows g*128+64 + [0,64), BN fused ----
        for (int u = t; u < 704; u += 256) {
            int oc = u / 11, iq = u - oc * 11, i0 = iq * 4;
            int o = g * 128 + 64 + oc;
            const float* wrow = Wq + o * 256;
            float a0 = 0.f, a1 = 0.f, a2 = 0.f, a3 = 0.f;
            #pragma unroll 4
            for (int c = 0; c < 256; ++c) {
                float wv = wrow[c];
                float4 xv = *(const float4*)&Xs[c][i0];
                a0 += wv * xv.x; a1 += wv * xv.y; a2 += wv * xv.z; a3 += wv * xv.w;
            }
            float s = bnq[o] * rsqrtf(bnq[1536 + o] + EPSV);
            float h = bnq[512 + o] - bnq[1024 + o] * s;
            *(float4*)&qb[oc][i0] = make_float4(a0 * s + h, a1 * s + h, a2 * s + h, a3 * s + h);
        }

        // ---- softmax over j, wave-per-row (independent of v-GEMM above) ----
        {
            int wv = t >> 6, lane = t & 63;
            for (int i = wv; i < 44; i += 4) {
                float v = (lane < 44) ? sc[i][lane] : -INFINITY;
                float m = v;
                #pragma unroll
                for (int off = 32; off; off >>= 1) m = fmaxf(m, __shfl_xor(m, off));
                float ex = (lane < 44) ? __expf(v - m) : 0.f;
                float ssum = ex;
                #pragma unroll
                for (int off = 32; off; off >>= 1) ssum += __shfl_xor(ssum, off);
                if (lane < 44) sc[i][lane] = ex / ssum;
            }
        }
        __syncthreads();

        // ---- outputs: sv + sve, bn_out fused, pair-summed ----
        for (int e = t; e < 2816; e += 256) {
            int c = e / 44, i = e - c * 44;
            const float4* srow = (const float4*)&sc[i][0];
            const float4* vrow = (const float4*)&qb[c][0];
            float asv = 0.f;
            #pragma unroll
            for (int jj = 0; jj < 11; ++jj) {
                float4 s4 = srow[jj], v4 = vrow[jj];
                asv += s4.x * v4.x + s4.y * v4.y + s4.z * v4.z + s4.w * v4.w;
            }
            const float* relv = rel + (64 + c) * 87 + i + 43;  // rows 64..127
            float asve = 0.f;
            #pragma unroll 4
            for (int j = 0; j < 44; ++j) asve += sc[i][j] * relv[-j];

            int o0 = g * 128 + 2 * c;
            float s0 = bno[o0]     * rsqrtf(bno[1536 + o0] + EPSV);
            float h0 = bno[512 + o0] - bno[1024 + o0] * s0;
            float s1 = bno[o0 + 1] * rsqrtf(bno[1537 + o0] + EPSV);
            float h1 = bno[513 + o0] - bno[1025 + o0] * s1;
            float val = s0 * asv + h0 + s1 * (0.1f * asve) + h1;

            int cf = g * 64 + c;
            if (!WIDTH) {
                pout[((n * 256 + cf) * 44 + i) * 44 + col] = val;
            } else {
                float r = xres[((b * 256 + cf) * 88 + i2 * 44 + col) * 88 + i4 * 44 + i];
                pout[((n * 256 + cf) * 44 + col) * 44 + i] = val + r;
            }
        }
        __syncthreads();   // qb/sc reused next group
    }
}

// ---------------------------------------------------------------------------
// 3x3 SAME conv, fp32, fused un-patchify + bias.
// Grid (11 ybands, 16 co-tiles, 64 n); block 256 = 4 waves.
// Wave wv -> 4 output channels; lane<44 -> x; each thread: acc[4co][4y].
// LDS: input tile 32ci x 6rows x 46cols + weight tile 16co x 32ci x 9.
// ---------------------------------------------------------------------------
__global__ __launch_bounds__(256)
void conv_kernel(const float* __restrict__ p,
                 const float* __restrict__ cw,   // 256,256,3,3
                 const float* __restrict__ cb,
                 float* __restrict__ out)
{
    __shared__ float sIn[32][6][46];
    __shared__ float sW[16][32][9];

    const int yb = blockIdx.x, cot = blockIdx.y, n = blockIdx.z;
    const int y0 = yb * 4, co0 = cot * 16;
    const int b = n >> 2, i2 = (n >> 1) & 1, i4 = n & 1;
    const int t = threadIdx.x;
    const int wv = t >> 6, lane = t & 63;

    float acc[4][4];
    #pragma unroll
    for (int a = 0; a < 4; ++a)
        #pragma unroll
        for (int y = 0; y < 4; ++y) acc[a][y] = 0.f;

    for (int ci0 = 0; ci0 < 256; ci0 += 32) {
        __syncthreads();
        // input tile: rows y0-1..y0+4, cols -1..44 (zero-padded)
        for (int m = t; m < 32 * 6 * 46; m += 256) {
            int ci = m / 276, rem = m - ci * 276;
            int rr = rem / 46, cc = rem - rr * 46;
            int y = y0 - 1 + rr, xg = cc - 1;
            float v = 0.f;
            if (y >= 0 && y < 44 && xg >= 0 && xg < 44)
                v = p[((n * 256 + ci0 + ci) * 44 + y) * 44 + xg];
            sIn[ci][rr][cc] = v;
        }
        // weight tile
        for (int m = t; m < 16 * 32 * 9; m += 256) {
            int co = m / 288, rem = m - co * 288;
            int ci = rem / 9, k = rem - ci * 9;
            sW[co][ci][k] = cw[((co0 + co) * 256 + ci0 + ci) * 9 + k];
        }
        __syncthreads();

        if (lane < 44) {
            const int x = lane;
            for (int ci = 0; ci < 32; ++ci) {
                float in[6][3];
                #pragma unroll
                for (int r = 0; r < 6; ++r) {
                    in[r][0] = sIn[ci][r][x];
                    in[r][1] = sIn[ci][r][x + 1];
                    in[r][2] = sIn[ci][r][x + 2];
                }
                #pragma unroll
                for (int a = 0; a < 4; ++a) {
                    const float* wr = &sW[wv * 4 + a][ci][0];
                    float w0 = wr[0], w1 = wr[1], w2 = wr[2];
                    float w3 = wr[3], w4 = wr[4], w5 = wr[5];
                    float w6 = wr[6], w7 = wr[7], w8 = wr[8];
                    #pragma unroll
                    for (int yy = 0; yy < 4; ++yy) {
                        acc[a][yy] += w0 * in[yy][0]     + w1 * in[yy][1]     + w2 * in[yy][2]
                                    + w3 * in[yy + 1][0] + w4 * in[yy + 1][1] + w5 * in[yy + 1][2]
                                    + w6 * in[yy + 2][0] + w7 * in[yy + 2][1] + w8 * in[yy + 2][2];
                    }
                }
            }
        }
    }

    if (lane < 44) {
        #pragma unroll
        for (int a = 0; a < 4; ++a) {
            int co = co0 + wv * 4 + a;
            float bias = cb[co];
            #pragma unroll
            for (int yy = 0; yy < 4; ++yy) {
                int y = y0 + yy;
                out[((b * 256 + co) * 88 + i2 * 44 + y) * 88 + i4 * 44 + lane] = acc[a][yy] + bias;
            }
        }
    }
}

extern "C" void kernel_launch(void* const* d_in, const int* in_sizes, int n_in,
                              void* d_out, int out_size, void* d_ws, size_t ws_size,
                              hipStream_t stream)
{
    (void)in_sizes; (void)n_in; (void)out_size; (void)ws_size;

    const float* x        = (const float*)d_in[0];
    const float* h_qkv_w  = (const float*)d_in[1];
    const float* h_bn_qkv = (const float*)d_in[2];
    const float* h_bn_sim = (const float*)d_in[3];
    const float* h_bn_out = (const float*)d_in[4];
    const float* h_rel    = (const float*)d_in[5];
    const float* w_qkv_w  = (const float*)d_in[6];
    const float* w_bn_qkv = (const float*)d_in[7];
    const float* w_bn_sim = (const float*)d_in[8];
    const float* w_bn_out = (const float*)d_in[9];
    const float* w_rel    = (const float*)d_in[10];
    const float* conv_w   = (const float*)d_in[11];
    const float* conv_b   = (const float*)d_in[12];

    float* p = (float*)d_ws;           // 64*256*44*44 floats = 126.9 MB
    float* o = (float*)d_out;

    // height-axis attention: patchified x -> p
    axial_kernel<false><<<2816, 256, 0, stream>>>(x, nullptr, p,
        h_qkv_w, h_bn_qkv, h_bn_sim, h_bn_out, h_rel);
    // width-axis attention, in-place on p, + residual (patchified x)
    axial_kernel<true><<<2816, 256, 0, stream>>>(p, x, p,
        w_qkv_w, w_bn_qkv, w_bn_sim, w_bn_out, w_rel);
    // conv3x3 + bias, fused un-patchify -> out
    conv_kernel<<<dim3(11, 16, 64), 256, 0, stream>>>(p, conv_w, conv_b, o);
}

// Round 2
// 4491.195 us; speedup vs baseline: 1.7818x; 1.7818x over previous
//
#include <hip/hip_runtime.h>
#include <math.h>

#define EPSV 1e-5f

typedef unsigned short ushort_t;
typedef __attribute__((ext_vector_type(8))) short bf16x8;
typedef __attribute__((ext_vector_type(8))) unsigned short u16x8;
typedef __attribute__((ext_vector_type(4))) float f32x4;

#define N_P 31719424   // 64*256*44*44 elements of p
#define N_W 589824     // 256*256*9 conv weights

// split-bf16 conv weights, fragment-ordered (rewritten every launch)
__device__ ushort_t g_whi[N_W];
__device__ ushort_t g_wlo[N_W];

__device__ __forceinline__ ushort_t f2bf_rn(float f) {
    unsigned int u = __float_as_uint(f);
    unsigned int r = u + 0x7FFFu + ((u >> 16) & 1u);
    return (ushort_t)(r >> 16);
}
__device__ __forceinline__ float bf2f(ushort_t h) {
    return __uint_as_float(((unsigned int)h) << 16);
}

// ---------------------------------------------------------------------------
// Weight split + swizzle into MFMA A-fragment order:
// didx = (((cit*9+tap)*4+ci8)*256+co)*8 + e   (cit=ci>>5, ci8=(ci&31)>>3, e=ci&7)
// ---------------------------------------------------------------------------
__global__ __launch_bounds__(256)
void wsplit_kernel(const float* __restrict__ cw)
{
    int idx = blockIdx.x * 256 + threadIdx.x;
    if (idx >= N_W) return;
    int tap = idx % 9;
    int rem = idx / 9;
    int ci = rem & 255, co = rem >> 8;
    float w = cw[idx];
    ushort_t hi = f2bf_rn(w);
    ushort_t lo = f2bf_rn(w - bf2f(hi));
    int cit = ci >> 5, ci5 = ci & 31, ci8 = ci5 >> 3, e = ci5 & 7;
    int didx = (((cit * 9 + tap) * 4 + ci8) * 256 + co) * 8 + e;
    g_whi[didx] = hi;
    g_wlo[didx] = lo;
}

// ---------------------------------------------------------------------------
// Axial attention megakernel (fp32 math, unchanged): one block per column.
//  WIDTH=false: reads original x (patchify indexing), writes p_hi/p_lo
//               channels-last [n][y][x][c] as split bf16.
//  WIDTH=true : reads p_hi/p_lo (reconstruct hi+lo), adds residual, writes
//               p_hi/p_lo in place (block-disjoint ranges -> safe).
// ---------------------------------------------------------------------------
template<bool WIDTH>
__global__ __launch_bounds__(256)
void axial_kernel(const float* __restrict__ xsrc,
                  const ushort_t* phi_in, const ushort_t* plo_in,
                  ushort_t* phi_out, ushort_t* plo_out,
                  const float* __restrict__ Wq,    // 512x256
                  const float* __restrict__ bnq,   // 4x512
                  const float* __restrict__ bns,   // 4x12
                  const float* __restrict__ bno,   // 4x512
                  const float* __restrict__ rel)   // 128x87
{
    __shared__ __align__(16) float Xs[256][44];
    __shared__ __align__(16) float qb[64][44];
    __shared__ __align__(16) float sc[44][44];

    const int blk = blockIdx.x;
    const int n   = blk / 44;
    const int col = blk - n * 44;
    const int b = n >> 2, i2 = (n >> 1) & 1, i4 = n & 1;
    const int t = threadIdx.x;

    // ---- stage X[c][i] ----
    if (!WIDTH) {
        const float* base = xsrc + ((b * 256) * 88 + i2 * 44) * 88 + i4 * 44 + col;
        for (int e = t; e < 256 * 44; e += 256) {
            int c = e / 44, i = e - c * 44;
            Xs[c][i] = base[c * 7744 + i * 88];
        }
    } else {
        const ushort_t* ph = phi_in + (size_t)(n * 44 + col) * 44 * 256;
        const ushort_t* pl = plo_in + (size_t)(n * 44 + col) * 44 * 256;
        for (int e = t; e < 11264; e += 256) {   // e = i*256 + c
            int i = e >> 8, c = e & 255;
            Xs[c][i] = bf2f(ph[e]) + bf2f(pl[e]);
        }
    }
    __syncthreads();

    for (int g = 0; g < 4; ++g) {
        // ---- q,k rows ----
        for (int u = t; u < 704; u += 256) {
            int oc = u / 11, iq = u - oc * 11, i0 = iq * 4;
            int o = g * 128 + oc;
            const float* wrow = Wq + o * 256;
            float a0 = 0.f, a1 = 0.f, a2 = 0.f, a3 = 0.f;
            #pragma unroll 4
            for (int c = 0; c < 256; ++c) {
                float wv = wrow[c];
                float4 xv = *(const float4*)&Xs[c][i0];
                a0 += wv * xv.x; a1 += wv * xv.y; a2 += wv * xv.z; a3 += wv * xv.w;
            }
            float s = bnq[o] * rsqrtf(bnq[1536 + o] + EPSV);
            float h = bnq[512 + o] - bnq[1024 + o] * s;
            *(float4*)&qb[oc][i0] = make_float4(a0 * s + h, a1 * s + h, a2 * s + h, a3 * s + h);
        }
        __syncthreads();

        // ---- scores ----
        const float sqk = bns[g]     * rsqrtf(bns[36 + g] + EPSV);
        const float sqr = bns[4 + g] * rsqrtf(bns[40 + g] + EPSV);
        const float skr = bns[8 + g] * rsqrtf(bns[44 + g] + EPSV);

        for (int e = t; e < 1936; e += 256) {
            int i = e / 44, j = e - i * 44;
            const float* relq = rel + (i - j + 43);
            const float* relk = rel + 32 * 87 + (j - i + 43);
            float aqk = 0.f, aqr = 0.f, akr = 0.f;
            #pragma unroll 4
            for (int c = 0; c < 32; ++c) {
                float qi = qb[c][i], kj = qb[32 + c][j];
                aqk += qi * kj;
                aqr += qi * relq[c * 87];
                akr += kj * relk[c * 87];
            }
            sc[i][j] = sqk * aqk + 0.1f * (sqr * aqr + skr * akr);
        }
        __syncthreads();

        // ---- v rows overwrite qb ----
        for (int u = t; u < 704; u += 256) {
            int oc = u / 11, iq = u - oc * 11, i0 = iq * 4;
            int o = g * 128 + 64 + oc;
            const float* wrow = Wq + o * 256;
            float a0 = 0.f, a1 = 0.f, a2 = 0.f, a3 = 0.f;
            #pragma unroll 4
            for (int c = 0; c < 256; ++c) {
                float wv = wrow[c];
                float4 xv = *(const float4*)&Xs[c][i0];
                a0 += wv * xv.x; a1 += wv * xv.y; a2 += wv * xv.z; a3 += wv * xv.w;
            }
            float s = bnq[o] * rsqrtf(bnq[1536 + o] + EPSV);
            float h = bnq[512 + o] - bnq[1024 + o] * s;
            *(float4*)&qb[oc][i0] = make_float4(a0 * s + h, a1 * s + h, a2 * s + h, a3 * s + h);
        }

        // ---- softmax (wave per row) ----
        {
            int wv = t >> 6, lane = t & 63;
            for (int i = wv; i < 44; i += 4) {
                float v = (lane < 44) ? sc[i][lane] : -INFINITY;
                float m = v;
                #pragma unroll
                for (int off = 32; off; off >>= 1) m = fmaxf(m, __shfl_xor(m, off));
                float ex = (lane < 44) ? __expf(v - m) : 0.f;
                float ssum = ex;
                #pragma unroll
                for (int off = 32; off; off >>= 1) ssum += __shfl_xor(ssum, off);
                if (lane < 44) sc[i][lane] = ex / ssum;
            }
        }
        __syncthreads();

        // ---- outputs: sv + sve, bn_out fused, pair-summed; split-bf16 store ----
        for (int e = t; e < 2816; e += 256) {   // c fastest for coalesced bf16 writes
            int c = e & 63, i = e >> 6;
            const float4* srow = (const float4*)&sc[i][0];
            const float4* vrow = (const float4*)&qb[c][0];
            float asv = 0.f;
            #pragma unroll
            for (int jj = 0; jj < 11; ++jj) {
                float4 s4 = srow[jj], v4 = vrow[jj];
                asv += s4.x * v4.x + s4.y * v4.y + s4.z * v4.z + s4.w * v4.w;
            }
            const float* relv = rel + (64 + c) * 87 + i + 43;
            float asve = 0.f;
            #pragma unroll 4
            for (int j = 0; j < 44; ++j) asve += sc[i][j] * relv[-j];

            int o0 = g * 128 + 2 * c;
            float s0 = bno[o0]     * rsqrtf(bno[1536 + o0] + EPSV);
            float h0 = bno[512 + o0] - bno[1024 + o0] * s0;
            float s1 = bno[o0 + 1] * rsqrtf(bno[1537 + o0] + EPSV);
            float h1 = bno[513 + o0] - bno[1025 + o0] * s1;
            float val = s0 * asv + h0 + s1 * (0.1f * asve) + h1;

            int cf = g * 64 + c;
            size_t idx;
            if (!WIDTH) {
                // element is (y=i, x=col)
                idx = ((size_t)(n * 44 + i) * 44 + col) * 256 + cf;
            } else {
                // element is (y=col, x=i); add residual
                float r = xsrc[((b * 256 + cf) * 88 + i2 * 44 + col) * 88 + i4 * 44 + i];
                val += r;
                idx = ((size_t)(n * 44 + col) * 44 + i) * 256 + cf;
            }
            ushort_t hi = f2bf_rn(val);
            ushort_t lo = f2bf_rn(val - bf2f(hi));
            phi_out[idx] = hi;
            plo_out[idx] = lo;
        }
        __syncthreads();
    }
}

// ---------------------------------------------------------------------------
// 3x3 SAME conv as implicit GEMM, split-bf16 MFMA (16x16x32), fused
// un-patchify + bias. Block: 256 thr = 4 waves; tile co=256 x px=(2y x 48x).
// Wave w: co [w*64, w*64+64) (4 m-frags) x all 6 n-frags. K = 8 ci-tiles x 9 taps.
// LDS: input tile [4 rows][50 cols][32 ci] hi+lo, XOR-swizzled 16B chunks.
// ---------------------------------------------------------------------------
__global__ __launch_bounds__(256)
void conv_kernel(const ushort_t* __restrict__ phi,
                 const ushort_t* __restrict__ plo,
                 const float* __restrict__ cb,
                 float* __restrict__ out)
{
    __shared__ __align__(16) ushort_t Xs2[2][4 * 50 * 32];   // hi, lo: 12800 B each

    const int yb = blockIdx.x, n = blockIdx.y;
    const int y0 = yb * 2;
    const int b = n >> 2, i2 = (n >> 1) & 1, i4 = n & 1;
    const int t = threadIdx.x;
    const int wv = t >> 6, lane = t & 63;
    const int l15 = lane & 15, l16 = lane >> 4;

    f32x4 acc[4][6];
    #pragma unroll
    for (int mf = 0; mf < 4; ++mf)
        #pragma unroll
        for (int nf = 0; nf < 6; ++nf) acc[mf][nf] = (f32x4)0.f;

    char* lds = (char*)&Xs2[0][0];

    for (int cit = 0; cit < 8; ++cit) {
        const int ci0 = cit * 32;
        __syncthreads();
        // ---- stage input tile: rows y0-1..y0+2, cols x=-1..48, 32 ci, hi+lo ----
        for (int m = t; m < 1600; m += 256) {
            int ci8 = m & 3;
            int rem = m >> 2;            // < 400
            int col = rem % 50;
            int rr  = rem / 50;          // < 8
            int arr = rr >> 2, rowidx = rr & 3;
            int gy = y0 - 1 + rowidx, gx = col - 1;
            u16x8 v = (u16x8)0;
            if (gy >= 0 && gy < 44 && gx >= 0 && gx < 44) {
                const ushort_t* src = (arr ? plo : phi)
                    + (size_t)((n * 44 + gy) * 44 + gx) * 256 + ci0 + ci8 * 8;
                v = *(const u16x8*)src;
            }
            unsigned int addr = (unsigned int)((rowidx * 50 + col) * 64 + ci8 * 16);
            addr ^= ((col & 7) << 4);
            *(u16x8*)(lds + arr * 12800 + addr) = v;
        }
        __syncthreads();

        for (int tap = 0; tap < 9; ++tap) {
            const int dy = tap / 3, dx = tap % 3;

            // A-fragments (hi/lo) from L2-resident fragment-ordered weights
            const size_t wb = ((size_t)((cit * 9 + tap) * 4 + l16) * 256 + wv * 64 + l15) * 8;
            const u16x8* wh = (const u16x8*)(g_whi + wb);
            const u16x8* wl = (const u16x8*)(g_wlo + wb);
            bf16x8 ah[4], al[4];
            #pragma unroll
            for (int mf = 0; mf < 4; ++mf) {
                ah[mf] = (bf16x8)wh[mf * 16];
                al[mf] = (bf16x8)wl[mf * 16];
            }

            // per-lane swizzled B base (ry=0, cb=0)
            int colr = l15 + dx;
            unsigned int rbase = (unsigned int)((dy * 50 + colr) * 64 + l16 * 16);
            rbase ^= ((colr & 7) << 4);
            const char* hb = lds + rbase;

            #pragma unroll
            for (int nf = 0; nf < 6; ++nf) {
                const int ry = nf / 3, cbk = nf % 3;
                const int off = ry * 3200 + cbk * 1024;
                bf16x8 bh = *(const bf16x8*)(hb + off);
                bf16x8 bl = *(const bf16x8*)(hb + 12800 + off);
                #pragma unroll
                for (int mf = 0; mf < 4; ++mf) {
                    acc[mf][nf] = __builtin_amdgcn_mfma_f32_16x16x32_bf16(ah[mf], bh, acc[mf][nf], 0, 0, 0);
                    acc[mf][nf] = __builtin_amdgcn_mfma_f32_16x16x32_bf16(al[mf], bh, acc[mf][nf], 0, 0, 0);
                    acc[mf][nf] = __builtin_amdgcn_mfma_f32_16x16x32_bf16(ah[mf], bl, acc[mf][nf], 0, 0, 0);
                }
            }
        }
    }

    // ---- store: D row = co = (lane>>4)*4 + reg (+16*mf +64*wv), col = px = lane&15 ----
    #pragma unroll
    for (int mf = 0; mf < 4; ++mf) {
        const int cobase = wv * 64 + mf * 16 + l16 * 4;
        float bias[4];
        #pragma unroll
        for (int r = 0; r < 4; ++r) bias[r] = cb[cobase + r];
        #pragma unroll
        for (int nf = 0; nf < 6; ++nf) {
            const int ry = nf / 3, cbk = nf % 3;
            const int x = cbk * 16 + l15;
            if (x < 44) {
                const int y = y0 + ry;
                #pragma unroll
                for (int r = 0; r < 4; ++r) {
                    const int co = cobase + r;
                    out[((size_t)(b * 256 + co) * 88 + i2 * 44 + y) * 88 + i4 * 44 + x]
                        = acc[mf][nf][r] + bias[r];
                }
            }
        }
    }
}

extern "C" void kernel_launch(void* const* d_in, const int* in_sizes, int n_in,
                              void* d_out, int out_size, void* d_ws, size_t ws_size,
                              hipStream_t stream)
{
    (void)in_sizes; (void)n_in; (void)out_size; (void)ws_size;

    const float* x        = (const float*)d_in[0];
    const float* h_qkv_w  = (const float*)d_in[1];
    const float* h_bn_qkv = (const float*)d_in[2];
    const float* h_bn_sim = (const float*)d_in[3];
    const float* h_bn_out = (const float*)d_in[4];
    const float* h_rel    = (const float*)d_in[5];
    const float* w_qkv_w  = (const float*)d_in[6];
    const float* w_bn_qkv = (const float*)d_in[7];
    const float* w_bn_sim = (const float*)d_in[8];
    const float* w_bn_out = (const float*)d_in[9];
    const float* w_rel    = (const float*)d_in[10];
    const float* conv_w   = (const float*)d_in[11];
    const float* conv_b   = (const float*)d_in[12];

    ushort_t* phi = (ushort_t*)d_ws;          // 63.4 MB
    ushort_t* plo = phi + N_P;                // 63.4 MB
    float* o = (float*)d_out;

    // split conv weights into fragment order (device globals)
    wsplit_kernel<<<(N_W + 255) / 256, 256, 0, stream>>>(conv_w);

    // height-axis attention: x -> split-bf16 p (channels-last)
    axial_kernel<false><<<2816, 256, 0, stream>>>(x, nullptr, nullptr, phi, plo,
        h_qkv_w, h_bn_qkv, h_bn_sim, h_bn_out, h_rel);
    // width-axis attention, in place, + residual
    axial_kernel<true><<<2816, 256, 0, stream>>>(x, phi, plo, phi, plo,
        w_qkv_w, w_bn_qkv, w_bn_sim, w_bn_out, w_rel);
    // conv3x3 via split-bf16 MFMA + bias, fused un-patchify
    conv_kernel<<<dim3(22, 64), 256, 0, stream>>>(phi, plo, conv_b, o);
}